// Round 6
// baseline (178.785 us; speedup 1.0000x reference)
//
#include <hip/hip_runtime.h>
#include <hip/hip_bf16.h>
#include <math.h>

#define B_  64
#define S_  128
#define E_  512
#define H_  1024
#define V_  32000
#define H3_ 3072
#define NT_ 16

typedef __attribute__((ext_vector_type(8))) short bf16x8;
typedef __attribute__((ext_vector_type(4))) float f32x4;

__device__ __forceinline__ unsigned short f2b(float f) {
    unsigned int u = __builtin_bit_cast(unsigned int, f);
    u = (u + 0x7fffu + ((u >> 16) & 1u)) >> 16;
    return (unsigned short)u;
}

// ---------------------------------------------------------------------------
// fp32 64x64-tile inner product over a K span
// ---------------------------------------------------------------------------
__device__ __forceinline__ void tile_acc(const float* __restrict__ A, int lda,
                                         const float* __restrict__ Wrow0, int ldw,
                                         int kspan, int t, float c[4][4],
                                         float (*As)[64], float (*Ws)[64]) {
    const int tx = t & 15, ty = t >> 4;
    const int lm = t >> 2;
    const int lk = (t & 3) * 4;
    for (int k0 = 0; k0 < kspan; k0 += 16) {
        float4 av = *(const float4*)&A[lm * lda + k0 + lk];
        float4 wv = *(const float4*)&Wrow0[(size_t)lm * ldw + k0 + lk];
        As[lk + 0][lm] = av.x; As[lk + 1][lm] = av.y;
        As[lk + 2][lm] = av.z; As[lk + 3][lm] = av.w;
        Ws[lk + 0][lm] = wv.x; Ws[lk + 1][lm] = wv.y;
        Ws[lk + 2][lm] = wv.z; Ws[lk + 3][lm] = wv.w;
        __syncthreads();
        #pragma unroll
        for (int k = 0; k < 16; ++k) {
            float4 a = *(const float4*)&As[k][ty * 4];
            float4 w = *(const float4*)&Ws[k][tx * 4];
            c[0][0] += a.x * w.x; c[0][1] += a.x * w.y; c[0][2] += a.x * w.z; c[0][3] += a.x * w.w;
            c[1][0] += a.y * w.x; c[1][1] += a.y * w.y; c[1][2] += a.y * w.z; c[1][3] += a.y * w.w;
            c[2][0] += a.z * w.x; c[2][1] += a.z * w.y; c[2][2] += a.z * w.z; c[2][3] += a.z * w.w;
            c[3][0] += a.w * w.x; c[3][1] += a.w * w.y; c[3][2] += a.w * w.z; c[3][3] += a.w * w.w;
        }
        __syncthreads();
    }
}

__device__ __forceinline__ void hproj_body(int bx, int by, const float* __restrict__ h,
                                           const float* __restrict__ Wa, float* __restrict__ hpp,
                                           int t, float (*As)[64], float (*Ws)[64]) {
    const int n0 = bx * 64;
    const int kb = by * 128;
    const int tx = t & 15, ty = t >> 4;
    float c[4][4];
    #pragma unroll
    for (int i = 0; i < 4; ++i)
        #pragma unroll
        for (int j = 0; j < 4; ++j) c[i][j] = 0.f;
    tile_acc(&h[kb], H_, &Wa[(size_t)n0 * (2 * H_) + kb], 2 * H_, 128, t, c, As, Ws);
    float* dst = hpp + (size_t)by * B_ * H_;
    #pragma unroll
    for (int i = 0; i < 4; ++i) {
        const int m = ty * 4 + i;
        #pragma unroll
        for (int j = 0; j < 4; ++j)
            dst[m * H_ + n0 + tx * 4 + j] = c[i][j];
    }
}

// one gate split-K chunk: sel 0: emb@Wx k0-512 ; 1,2: z@Wz ; 3,4: h@Wh -> P[c]
__device__ __forceinline__ void gate_body(int n0, int sel,
                                          const float* __restrict__ emb, const float* __restrict__ z,
                                          const float* __restrict__ h,
                                          const float* __restrict__ Wx, const float* __restrict__ Wz,
                                          const float* __restrict__ Wh, float* __restrict__ P,
                                          int t, float (*As)[64], float (*Ws)[64]) {
    const int tx = t & 15, ty = t >> 4;
    const float* A; const float* W; int lda, kb, chunk;
    if (sel == 0)      { A = emb; W = Wx; lda = E_; kb = 0;   chunk = 0; }
    else if (sel == 1) { A = z;   W = Wz; lda = H_; kb = 0;   chunk = 1; }
    else if (sel == 2) { A = z;   W = Wz; lda = H_; kb = 512; chunk = 2; }
    else if (sel == 3) { A = h;   W = Wh; lda = H_; kb = 0;   chunk = 5; }
    else               { A = h;   W = Wh; lda = H_; kb = 512; chunk = 6; }
    float c[4][4];
    #pragma unroll
    for (int i = 0; i < 4; ++i)
        #pragma unroll
        for (int j = 0; j < 4; ++j) c[i][j] = 0.f;
    tile_acc(&A[kb], lda, &W[(size_t)n0 * lda + kb], lda, 512, t, c, As, Ws);
    float* dst = P + (size_t)chunk * B_ * H3_;
    #pragma unroll
    for (int i = 0; i < 4; ++i) {
        const int m = ty * 4 + i;
        #pragma unroll
        for (int j = 0; j < 4; ++j)
            dst[m * H3_ + n0 + tx * 4 + j] = c[i][j];
    }
}

// ---------------------------------------------------------------------------
// Fused prologue (all independent work, overlapping BW- and VALU-bound blocks):
// [0,4096)      cast enc -> bf16
// [4096,4608)   cast Wa2 -> bf16
// [4608,4736)   hproj split-K partials
// [4736,4976)   gate split-K chunks {emb,z,h} (ctx chunks run later)
// ---------------------------------------------------------------------------
__global__ __launch_bounds__(256) void prologue(
    const float* __restrict__ enc, const float* __restrict__ Wa,
    const float* __restrict__ h, const float* __restrict__ emb,
    const float* __restrict__ z,
    const float* __restrict__ Wx, const float* __restrict__ Wz,
    const float* __restrict__ Wh,
    unsigned short* __restrict__ encb, unsigned short* __restrict__ wa2b,
    float* __restrict__ hpp, float* __restrict__ P) {
    __shared__ float As[16][64];
    __shared__ float Ws[16][64];
    const int bid = blockIdx.x;
    const int t = threadIdx.x;
    if (bid < 4096) {
        const size_t i8 = ((size_t)bid * 256 + t) * 8;
        float4 a = *(const float4*)&enc[i8];
        float4 b = *(const float4*)&enc[i8 + 4];
        unsigned short o[8] = { f2b(a.x), f2b(a.y), f2b(a.z), f2b(a.w),
                                f2b(b.x), f2b(b.y), f2b(b.z), f2b(b.w) };
        *(uint4*)&encb[i8] = *(uint4*)o;
    } else if (bid < 4608) {
        const int id = (bid - 4096) * 256 + t;
        const int n = id >> 7;
        const int kk = (id & 127) * 8;
        const float* src = &Wa[(size_t)n * (2 * H_) + H_ + kk];
        float4 a = *(const float4*)src;
        float4 b = *(const float4*)(src + 4);
        unsigned short o[8] = { f2b(a.x), f2b(a.y), f2b(a.z), f2b(a.w),
                                f2b(b.x), f2b(b.y), f2b(b.z), f2b(b.w) };
        *(uint4*)&wa2b[(size_t)n * H_ + kk] = *(uint4*)o;
    } else if (bid < 4736) {
        const int id = bid - 4608;
        hproj_body(id & 15, id >> 4, h, Wa, hpp, t, As, Ws);
    } else {
        const int id = bid - 4736;                 // 0..239
        gate_body((id % 48) * 64, id / 48, emb, z, h, Wx, Wz, Wh, P, t, As, Ws);
    }
}

// standalone hproj (fallback path)
__global__ void hproj_splitk(const float* __restrict__ h, const float* __restrict__ Wa,
                             float* __restrict__ hpp) {
    __shared__ float As[16][64];
    __shared__ float Ws[16][64];
    hproj_body(blockIdx.x, blockIdx.y, h, Wa, hpp, threadIdx.x, As, Ws);
}

__global__ void reduce_hproj(const float* __restrict__ hpp, const float* __restrict__ ba,
                             float* __restrict__ hproj) {
    const int idx = blockIdx.x * 256 + threadIdx.x;
    const int hh = idx & 1023;
    float s = ba[hh];
    #pragma unroll
    for (int c = 0; c < 8; ++c) s += hpp[(size_t)c * B_ * H_ + idx];
    hproj[idx] = s;
}

// ---------------------------------------------------------------------------
// bf16 MFMA energy+scores: 128x128 tile, BK=64, 4 waves, 16x16x32 MFMA.
// LDS rows of 128 B (64 bf16), 8 16B slots, sw = slot ^ (row & 7).
// ---------------------------------------------------------------------------
__global__ __launch_bounds__(256) void energy_mfma(
    const unsigned short* __restrict__ Ab, const unsigned short* __restrict__ Bb,
    const float* __restrict__ hproj, const float* __restrict__ v,
    float* __restrict__ partials) {
    __shared__ unsigned short As[128 * 64];   // 16 KB
    __shared__ unsigned short Bs[128 * 64];
    const int nb = blockIdx.x;
    const int mb = blockIdx.y;
    const int m0 = mb * 128, n0 = nb * 128;
    const int t = threadIdx.x;
    const int lane = t & 63, w = t >> 6;
    const int wr = w >> 1, wc = w & 1;

    f32x4 acc[4][4];
    #pragma unroll
    for (int i = 0; i < 4; ++i)
        #pragma unroll
        for (int j = 0; j < 4; ++j) acc[i][j] = (f32x4){0.f, 0.f, 0.f, 0.f};

    for (int k0 = 0; k0 < H_; k0 += 64) {
        // stage: 128 rows x 8 slots per tile = 1024 chunks, 4/thread each tile
        #pragma unroll
        for (int r = 0; r < 4; ++r) {
            const int c = r * 256 + t;
            const int row = c >> 3, slot = c & 7;
            const int sw = slot ^ (row & 7);
            uint4 da = *(const uint4*)&Ab[(size_t)(m0 + row) * H_ + k0 + slot * 8];
            *(uint4*)((char*)As + row * 128 + sw * 16) = da;
            uint4 db = *(const uint4*)&Bb[(size_t)(n0 + row) * H_ + k0 + slot * 8];
            *(uint4*)((char*)Bs + row * 128 + sw * 16) = db;
        }
        __syncthreads();
        #pragma unroll
        for (int kk = 0; kk < 2; ++kk) {
            bf16x8 a[4], b[4];
            #pragma unroll
            for (int i = 0; i < 4; ++i) {
                const int row = wr * 64 + i * 16 + (lane & 15);
                const int sw = (kk * 4 + (lane >> 4)) ^ (row & 7);
                a[i] = *(const bf16x8*)((const char*)As + row * 128 + sw * 16);
            }
            #pragma unroll
            for (int j = 0; j < 4; ++j) {
                const int row = wc * 64 + j * 16 + (lane & 15);
                const int sw = (kk * 4 + (lane >> 4)) ^ (row & 7);
                b[j] = *(const bf16x8*)((const char*)Bs + row * 128 + sw * 16);
            }
            #pragma unroll
            for (int i = 0; i < 4; ++i)
                #pragma unroll
                for (int j = 0; j < 4; ++j)
                    acc[i][j] = __builtin_amdgcn_mfma_f32_16x16x32_bf16(a[i], b[j], acc[i][j], 0, 0, 0);
        }
        __syncthreads();
    }

    float vj[4];
    #pragma unroll
    for (int j = 0; j < 4; ++j) vj[j] = v[n0 + wc * 64 + j * 16 + (lane & 15)];

    const int s = mb * 2 + wr;
    #pragma unroll
    for (int i = 0; i < 4; ++i) {
        #pragma unroll
        for (int q = 0; q < 4; ++q) {
            const int b = i * 16 + (lane >> 4) * 4 + q;
            float sum = 0.f;
            #pragma unroll
            for (int j = 0; j < 4; ++j) {
                const int n = n0 + wc * 64 + j * 16 + (lane & 15);
                sum += vj[j] * tanhf(acc[i][j][q] + hproj[b * H_ + n]);
            }
            sum += __shfl_xor(sum, 1);
            sum += __shfl_xor(sum, 2);
            sum += __shfl_xor(sum, 4);
            sum += __shfl_xor(sum, 8);
            if ((lane & 15) == 0)
                partials[((size_t)b * S_ + s) * NT_ + nb * 2 + wc] = sum;
        }
    }
}

// fp32 fallback energy (only if ws too small)
__global__ void energy_scores(const float* __restrict__ enc, const float* __restrict__ Wa,
                              const float* __restrict__ hproj, const float* __restrict__ v,
                              float* __restrict__ partials) {
    __shared__ float As[16][64];
    __shared__ float Ws[16][64];
    __shared__ float red[64][16];
    const int nt = blockIdx.x;
    const int s  = blockIdx.y;
    const int n0 = nt * 64;
    const float* Arow = enc + (size_t)s * (B_ * H_);
    const int t  = threadIdx.x;
    const int tx = t & 15, ty = t >> 4;
    float c[4][4];
    #pragma unroll
    for (int i = 0; i < 4; ++i)
        #pragma unroll
        for (int j = 0; j < 4; ++j) c[i][j] = 0.f;
    tile_acc(Arow, H_, &Wa[(size_t)n0 * (2 * H_) + H_], 2 * H_, H_, t, c, As, Ws);
    #pragma unroll
    for (int i = 0; i < 4; ++i) {
        const int b = ty * 4 + i;
        float part = 0.f;
        #pragma unroll
        for (int j = 0; j < 4; ++j) {
            const int h = n0 + tx * 4 + j;
            part += v[h] * tanhf(c[i][j] + hproj[b * H_ + h]);
        }
        red[b][tx] = part;
    }
    __syncthreads();
    if (t < 64) {
        float sum = 0.f;
        #pragma unroll
        for (int x = 0; x < 16; ++x) sum += red[t][x];
        partials[((size_t)t * S_ + s) * NT_ + nt] = sum;
    }
}

// ---------------------------------------------------------------------------
// Fused softmax + context: blockIdx.y = b, blockIdx.x = h-quarter
// ---------------------------------------------------------------------------
__global__ __launch_bounds__(256) void softmax_ctx(
    const float* __restrict__ spart, const float* __restrict__ enc,
    float* __restrict__ attn, float* __restrict__ ctx) {
    __shared__ float red[128];
    __shared__ float aw[128];
    const int b = blockIdx.y;
    const int t = threadIdx.x;
    if (t < 128) {
        float sc = 0.f;
        #pragma unroll
        for (int nt = 0; nt < NT_; ++nt) sc += spart[((size_t)b * S_ + t) * NT_ + nt];
        aw[t] = sc;
        red[t] = sc;
    }
    __syncthreads();
    for (int o = 64; o > 0; o >>= 1) {
        if (t < o) red[t] = fmaxf(red[t], red[t + o]);
        __syncthreads();
    }
    const float mx = red[0];
    __syncthreads();
    if (t < 128) { aw[t] = expf(aw[t] - mx); red[t] = aw[t]; }
    __syncthreads();
    for (int o = 64; o > 0; o >>= 1) {
        if (t < o) red[t] += red[t + o];
        __syncthreads();
    }
    const float inv = 1.f / red[0];
    if (t < 128) {
        aw[t] *= inv;
        if (blockIdx.x == 0) attn[b * S_ + t] = aw[t];
    }
    __syncthreads();
    const int h = blockIdx.x * 256 + t;
    float acc = 0.f;
    for (int s = 0; s < S_; ++s)
        acc += aw[s] * enc[((size_t)s * B_ + b) * H_ + h];
    ctx[b * H_ + h] = acc;
}

// ctx gate chunks (3,4) — run after softmax_ctx
__global__ void gates_ctx(const float* __restrict__ ctx, const float* __restrict__ Wc,
                          float* __restrict__ P) {
    __shared__ float As[16][64];
    __shared__ float Ws[16][64];
    const int n0 = blockIdx.x * 64;
    const int kb = blockIdx.y * 512;
    const int t  = threadIdx.x;
    const int tx = t & 15, ty = t >> 4;
    float c[4][4];
    #pragma unroll
    for (int i = 0; i < 4; ++i)
        #pragma unroll
        for (int j = 0; j < 4; ++j) c[i][j] = 0.f;
    tile_acc(&ctx[kb], H_, &Wc[(size_t)n0 * H_ + kb], H_, 512, t, c, As, Ws);
    float* dst = P + (size_t)(3 + blockIdx.y) * B_ * H3_;
    #pragma unroll
    for (int i = 0; i < 4; ++i) {
        const int m = ty * 4 + i;
        #pragma unroll
        for (int j = 0; j < 4; ++j)
            dst[m * H3_ + n0 + tx * 4 + j] = c[i][j];
    }
}

// fallback: all 7 gate chunks
__global__ void gates_splitk(const float* __restrict__ emb, const float* __restrict__ z,
                             const float* __restrict__ ctx, const float* __restrict__ h,
                             const float* __restrict__ Wx, const float* __restrict__ Wz,
                             const float* __restrict__ Wc, const float* __restrict__ Wh,
                             float* __restrict__ P) {
    __shared__ float As[16][64];
    __shared__ float Ws[16][64];
    const int n0 = blockIdx.x * 64;
    const int yc = blockIdx.y;
    const int t  = threadIdx.x;
    const int tx = t & 15, ty = t >> 4;
    const float* A; const float* W; int lda, kb;
    if (yc == 0)      { A = emb; W = Wx; lda = E_; kb = 0; }
    else if (yc <= 2) { A = z;   W = Wz; lda = H_; kb = (yc - 1) * 512; }
    else if (yc <= 4) { A = ctx; W = Wc; lda = H_; kb = (yc - 3) * 512; }
    else              { A = h;   W = Wh; lda = H_; kb = (yc - 5) * 512; }
    float c[4][4];
    #pragma unroll
    for (int i = 0; i < 4; ++i)
        #pragma unroll
        for (int j = 0; j < 4; ++j) c[i][j] = 0.f;
    tile_acc(&A[kb], lda, &W[(size_t)n0 * lda + kb], lda, 512, t, c, As, Ws);
    float* dst = P + (size_t)yc * B_ * H3_;
    #pragma unroll
    for (int i = 0; i < 4; ++i) {
        const int m = ty * 4 + i;
        #pragma unroll
        for (int j = 0; j < 4; ++j)
            dst[m * H3_ + n0 + tx * 4 + j] = c[i][j];
    }
}

// ---------------------------------------------------------------------------
// GRU elementwise (7-way reduce + biases) + fused bf16 cast of h_new
// ---------------------------------------------------------------------------
__global__ void gru_k(const float* __restrict__ P, const float* __restrict__ hlast,
                      const float* __restrict__ bx, const float* __restrict__ bz,
                      const float* __restrict__ bc, const float* __restrict__ bh,
                      float* __restrict__ hnew, unsigned short* __restrict__ hnewb) {
    const int idx = blockIdx.x * 256 + threadIdx.x;
    const int b = idx >> 10, h = idx & 1023;
    float x[3], hg[3];
    #pragma unroll
    for (int g = 0; g < 3; ++g) {
        const int col = g * H_ + h;
        float sx = bx[col] + bz[col] + bc[col];
        #pragma unroll
        for (int c = 0; c < 5; ++c) sx += P[((size_t)c * B_ + b) * H3_ + col];
        float sh = bh[col];
        #pragma unroll
        for (int c = 5; c < 7; ++c) sh += P[((size_t)c * B_ + b) * H3_ + col];
        x[g] = sx; hg[g] = sh;
    }
    const float r = 1.f / (1.f + expf(-(x[0] + hg[0])));
    const float u = 1.f / (1.f + expf(-(x[1] + hg[1])));
    const float n = tanhf(x[2] + r * hg[2]);
    const float val = (1.f - u) * n + u * hlast[idx];
    hnew[idx] = val;
    if (hnewb) hnewb[idx] = f2b(val);
}

// ---------------------------------------------------------------------------
// Wout bf16-MFMA GEMM, W fp32->bf16 converted during LDS staging
// ---------------------------------------------------------------------------
__global__ __launch_bounds__(256) void wout_mfma(
    const unsigned short* __restrict__ Ab, const float* __restrict__ W,
    const float* __restrict__ bias, float* __restrict__ C) {
    __shared__ unsigned short As[64 * 64];
    __shared__ unsigned short Bs[64 * 64];
    const int n0 = blockIdx.x * 64;
    const int t = threadIdx.x;
    const int lane = t & 63, w = t >> 6;
    const int wr = w >> 1, wc = w & 1;

    f32x4 acc[2][2];
    #pragma unroll
    for (int i = 0; i < 2; ++i)
        #pragma unroll
        for (int j = 0; j < 2; ++j) acc[i][j] = (f32x4){0.f, 0.f, 0.f, 0.f};

    for (int k0 = 0; k0 < H_; k0 += 64) {
        #pragma unroll
        for (int r = 0; r < 2; ++r) {
            const int c = r * 256 + t;
            const int row = c >> 3, slot = c & 7;
            const int sw = slot ^ (row & 7);
            uint4 da = *(const uint4*)&Ab[(size_t)row * H_ + k0 + slot * 8];
            *(uint4*)((char*)As + row * 128 + sw * 16) = da;
        }
        #pragma unroll
        for (int r = 0; r < 4; ++r) {
            const int c = r * 256 + t;
            const int row = c >> 4, q4 = c & 15;
            const float4 wv = *(const float4*)&W[(size_t)(n0 + row) * H_ + k0 + q4 * 4];
            uint2 pk;
            pk.x = (unsigned int)f2b(wv.x) | ((unsigned int)f2b(wv.y) << 16);
            pk.y = (unsigned int)f2b(wv.z) | ((unsigned int)f2b(wv.w) << 16);
            const int slot = q4 >> 1, half = q4 & 1;
            const int sw = slot ^ (row & 7);
            *(uint2*)((char*)Bs + row * 128 + sw * 16 + half * 8) = pk;
        }
        __syncthreads();
        #pragma unroll
        for (int kk = 0; kk < 2; ++kk) {
            bf16x8 a[2], b[2];
            #pragma unroll
            for (int i = 0; i < 2; ++i) {
                const int row = wr * 32 + i * 16 + (lane & 15);
                const int sw = (kk * 4 + (lane >> 4)) ^ (row & 7);
                a[i] = *(const bf16x8*)((const char*)As + row * 128 + sw * 16);
            }
            #pragma unroll
            for (int j = 0; j < 2; ++j) {
                const int row = wc * 32 + j * 16 + (lane & 15);
                const int sw = (kk * 4 + (lane >> 4)) ^ (row & 7);
                b[j] = *(const bf16x8*)((const char*)Bs + row * 128 + sw * 16);
            }
            #pragma unroll
            for (int i = 0; i < 2; ++i)
                #pragma unroll
                for (int j = 0; j < 2; ++j)
                    acc[i][j] = __builtin_amdgcn_mfma_f32_16x16x32_bf16(a[i], b[j], acc[i][j], 0, 0, 0);
        }
        __syncthreads();
    }

    #pragma unroll
    for (int i = 0; i < 2; ++i)
        #pragma unroll
        for (int j = 0; j < 2; ++j) {
            const int n = n0 + wc * 32 + j * 16 + (lane & 15);
            const float bn = bias[n];
            #pragma unroll
            for (int q = 0; q < 4; ++q) {
                const int m = wr * 32 + i * 16 + (lane >> 4) * 4 + q;
                C[(size_t)m * V_ + n] = acc[i][j][q] + bn;
            }
        }
}

// fp32 fallback Wout GEMM
__global__ void gemm_nt(const float* __restrict__ A, const float* __restrict__ W,
                        const float* __restrict__ bias, float* __restrict__ C,
                        int N, int K) {
    __shared__ float As[16][64];
    __shared__ float Ws[16][64];
    const int n0 = blockIdx.x * 64;
    const int t  = threadIdx.x;
    const int tx = t & 15, ty = t >> 4;
    float c[4][4];
    #pragma unroll
    for (int i = 0; i < 4; ++i)
        #pragma unroll
        for (int j = 0; j < 4; ++j) c[i][j] = 0.f;
    tile_acc(A, K, &W[(size_t)n0 * K], K, K, t, c, As, Ws);
    #pragma unroll
    for (int i = 0; i < 4; ++i) {
        const int m = ty * 4 + i;
        #pragma unroll
        for (int j = 0; j < 4; ++j) {
            const int n = n0 + tx * 4 + j;
            C[m * N + n] = c[i][j] + bias[n];
        }
    }
}

extern "C" void kernel_launch(void* const* d_in, const int* in_sizes, int n_in,
                              void* d_out, int out_size, void* d_ws, size_t ws_size,
                              hipStream_t stream) {
    const float* emb   = (const float*)d_in[0];
    const float* hid   = (const float*)d_in[1];
    const float* enc   = (const float*)d_in[2];
    const float* z     = (const float*)d_in[3];
    const float* Wa    = (const float*)d_in[4];
    const float* ba    = (const float*)d_in[5];
    const float* v     = (const float*)d_in[6];
    const float* Wx    = (const float*)d_in[7];
    const float* bx    = (const float*)d_in[8];
    const float* Wh    = (const float*)d_in[9];
    const float* bh    = (const float*)d_in[10];
    const float* Wc    = (const float*)d_in[11];
    const float* bc    = (const float*)d_in[12];
    const float* Wz    = (const float*)d_in[13];
    const float* bz    = (const float*)d_in[14];
    const float* Wout  = (const float*)d_in[15];
    const float* bout  = (const float*)d_in[16];

    float* out  = (float*)d_out;
    float* hnew = out + (size_t)B_ * V_;
    float* attn = hnew + (size_t)B_ * H_;

    // ws layout — fully disjoint (~27.5 MB; ws is ~512 MB)
    float* hproj = (float*)d_ws;                          // 64K f
    float* spart = hproj + (size_t)B_ * H_;               // 128K f
    float* ctx   = spart + (size_t)B_ * S_ * NT_;         // 64K f
    float* hpp   = ctx + (size_t)B_ * H_;                 // 512K f
    float* P     = hpp + (size_t)8 * B_ * H_;             // 1376K f
    float* fend  = P + (size_t)7 * B_ * H3_;
    unsigned short* hnewb = (unsigned short*)fend;        // 64K s
    unsigned short* encb  = hnewb + (size_t)B_ * H_;      // 8.39M s
    unsigned short* wa2b  = encb + (size_t)S_ * B_ * H_;  // 1.05M s
    const size_t need = (size_t)((char*)(wa2b + (size_t)H_ * H_) - (char*)d_ws);

    const float* hlast = hid;
    dim3 blk(256);

    const bool fast = (ws_size >= need);
    if (fast) {
        // casts + hproj split-K + non-ctx gate chunks, all fused/overlapped
        prologue<<<dim3(4976), blk, 0, stream>>>(enc, Wa, hlast, emb, z,
                                                 Wx, Wz, Wh, encb, wa2b, hpp, P);
        reduce_hproj<<<dim3((B_ * H_) / 256), blk, 0, stream>>>(hpp, ba, hproj);
        energy_mfma<<<dim3(H_ / 128, (S_ * B_) / 128), blk, 0, stream>>>(encb, wa2b, hproj, v, spart);
        softmax_ctx<<<dim3(H_ / 256, B_), blk, 0, stream>>>(spart, enc, attn, ctx);
        gates_ctx<<<dim3(H3_ / 64, 2), blk, 0, stream>>>(ctx, Wc, P);
        gru_k<<<dim3((B_ * H_) / 256), blk, 0, stream>>>(P, hlast, bx, bz, bc, bh, hnew, hnewb);
        wout_mfma<<<dim3(V_ / 64), blk, 0, stream>>>(hnewb, Wout, bout, out);
    } else {
        hproj_splitk<<<dim3(H_ / 64, 8), blk, 0, stream>>>(hlast, Wa, hpp);
        reduce_hproj<<<dim3((B_ * H_) / 256), blk, 0, stream>>>(hpp, ba, hproj);
        energy_scores<<<dim3(NT_, S_), blk, 0, stream>>>(enc, Wa, hproj, v, spart);
        softmax_ctx<<<dim3(H_ / 256, B_), blk, 0, stream>>>(spart, enc, attn, ctx);
        gates_splitk<<<dim3(H3_ / 64, 7), blk, 0, stream>>>(emb, z, ctx, hlast,
                                                            Wx, Wz, Wc, Wh, P);
        gru_k<<<dim3((B_ * H_) / 256), blk, 0, stream>>>(P, hlast, bx, bz, bc, bh, hnew, nullptr);
        gemm_nt<<<dim3(V_ / 64), blk, 0, stream>>>(hnew, Wout, bout, out, V_, H_);
    }
}

// Round 7
// 129.648 us; speedup vs baseline: 1.3790x; 1.3790x over previous
//
#include <hip/hip_runtime.h>
#include <hip/hip_bf16.h>
#include <math.h>

#define B_  64
#define S_  128
#define E_  512
#define H_  1024
#define V_  32000
#define H3_ 3072
#define NT_ 16
#define NGC 14   // gate split-K chunks of 256

typedef __attribute__((ext_vector_type(8))) short bf16x8;
typedef __attribute__((ext_vector_type(4))) float f32x4;

__device__ __forceinline__ unsigned short f2b(float f) {
    unsigned int u = __builtin_bit_cast(unsigned int, f);
    u = (u + 0x7fffu + ((u >> 16) & 1u)) >> 16;
    return (unsigned short)u;
}

// ---------------------------------------------------------------------------
// fp32 64x64-tile inner product over a K span, register-prefetch double buffer:
// next slab's loads issue right after the barrier, overlapping the FMA loop.
// ---------------------------------------------------------------------------
__device__ __forceinline__ void tile_acc(const float* __restrict__ A, int lda,
                                         const float* __restrict__ Wrow0, int ldw,
                                         int kspan, int t, float c[4][4],
                                         float (*As)[64], float (*Ws)[64]) {
    const int tx = t & 15, ty = t >> 4;
    const int lm = t >> 2;
    const int lk = (t & 3) * 4;
    float4 av = *(const float4*)&A[lm * lda + lk];
    float4 wv = *(const float4*)&Wrow0[(size_t)lm * ldw + lk];
    for (int k0 = 0; k0 < kspan; k0 += 16) {
        As[lk + 0][lm] = av.x; As[lk + 1][lm] = av.y;
        As[lk + 2][lm] = av.z; As[lk + 3][lm] = av.w;
        Ws[lk + 0][lm] = wv.x; Ws[lk + 1][lm] = wv.y;
        Ws[lk + 2][lm] = wv.z; Ws[lk + 3][lm] = wv.w;
        __syncthreads();
        if (k0 + 16 < kspan) {
            av = *(const float4*)&A[lm * lda + k0 + 16 + lk];
            wv = *(const float4*)&Wrow0[(size_t)lm * ldw + k0 + 16 + lk];
        }
        #pragma unroll
        for (int k = 0; k < 16; ++k) {
            float4 a = *(const float4*)&As[k][ty * 4];
            float4 w = *(const float4*)&Ws[k][tx * 4];
            c[0][0] += a.x * w.x; c[0][1] += a.x * w.y; c[0][2] += a.x * w.z; c[0][3] += a.x * w.w;
            c[1][0] += a.y * w.x; c[1][1] += a.y * w.y; c[1][2] += a.y * w.z; c[1][3] += a.y * w.w;
            c[2][0] += a.z * w.x; c[2][1] += a.z * w.y; c[2][2] += a.z * w.z; c[2][3] += a.z * w.w;
            c[3][0] += a.w * w.x; c[3][1] += a.w * w.y; c[3][2] += a.w * w.z; c[3][3] += a.w * w.w;
        }
        __syncthreads();
    }
}

__device__ __forceinline__ void hproj_body(int bx, int by, const float* __restrict__ h,
                                           const float* __restrict__ Wa, float* __restrict__ hpp,
                                           int t, float (*As)[64], float (*Ws)[64]) {
    const int n0 = bx * 64;
    const int kb = by * 128;
    const int tx = t & 15, ty = t >> 4;
    float c[4][4];
    #pragma unroll
    for (int i = 0; i < 4; ++i)
        #pragma unroll
        for (int j = 0; j < 4; ++j) c[i][j] = 0.f;
    tile_acc(&h[kb], H_, &Wa[(size_t)n0 * (2 * H_) + kb], 2 * H_, 128, t, c, As, Ws);
    float* dst = hpp + (size_t)by * B_ * H_;
    #pragma unroll
    for (int i = 0; i < 4; ++i) {
        const int m = ty * 4 + i;
        #pragma unroll
        for (int j = 0; j < 4; ++j)
            dst[m * H_ + n0 + tx * 4 + j] = c[i][j];
    }
}

// ---------------------------------------------------------------------------
// Fused prologue (R5 structure: casts + hproj ONLY — no long GEMM tail):
// [0,4096) cast enc->bf16 ; [4096,4608) cast Wa2->bf16 ; [4608,4736) hproj
// ---------------------------------------------------------------------------
__global__ __launch_bounds__(256) void prologue(
    const float* __restrict__ enc, const float* __restrict__ Wa,
    const float* __restrict__ h, unsigned short* __restrict__ encb,
    unsigned short* __restrict__ wa2b, float* __restrict__ hpp) {
    __shared__ float As[16][64];
    __shared__ float Ws[16][64];
    const int bid = blockIdx.x;
    const int t = threadIdx.x;
    if (bid < 4096) {
        const size_t i8 = ((size_t)bid * 256 + t) * 8;
        float4 a = *(const float4*)&enc[i8];
        float4 b = *(const float4*)&enc[i8 + 4];
        unsigned short o[8] = { f2b(a.x), f2b(a.y), f2b(a.z), f2b(a.w),
                                f2b(b.x), f2b(b.y), f2b(b.z), f2b(b.w) };
        *(uint4*)&encb[i8] = *(uint4*)o;
    } else if (bid < 4608) {
        const int id = (bid - 4096) * 256 + t;
        const int n = id >> 7;
        const int kk = (id & 127) * 8;
        const float* src = &Wa[(size_t)n * (2 * H_) + H_ + kk];
        float4 a = *(const float4*)src;
        float4 b = *(const float4*)(src + 4);
        unsigned short o[8] = { f2b(a.x), f2b(a.y), f2b(a.z), f2b(a.w),
                                f2b(b.x), f2b(b.y), f2b(b.z), f2b(b.w) };
        *(uint4*)&wa2b[(size_t)n * H_ + kk] = *(uint4*)o;
    } else {
        const int id = bid - 4608;
        hproj_body(id & 15, id >> 4, h, Wa, hpp, t, As, Ws);
    }
}

// standalone hproj (fallback path)
__global__ void hproj_splitk(const float* __restrict__ h, const float* __restrict__ Wa,
                             float* __restrict__ hpp) {
    __shared__ float As[16][64];
    __shared__ float Ws[16][64];
    hproj_body(blockIdx.x, blockIdx.y, h, Wa, hpp, threadIdx.x, As, Ws);
}

__global__ void reduce_hproj(const float* __restrict__ hpp, const float* __restrict__ ba,
                             float* __restrict__ hproj) {
    const int idx = blockIdx.x * 256 + threadIdx.x;
    const int hh = idx & 1023;
    float s = ba[hh];
    #pragma unroll
    for (int c = 0; c < 8; ++c) s += hpp[(size_t)c * B_ * H_ + idx];
    hproj[idx] = s;
}

// ---------------------------------------------------------------------------
// bf16 MFMA energy+scores: 128x128 tile, BK=64, 4 waves, 16x16x32 MFMA.
// ---------------------------------------------------------------------------
__global__ __launch_bounds__(256) void energy_mfma(
    const unsigned short* __restrict__ Ab, const unsigned short* __restrict__ Bb,
    const float* __restrict__ hproj, const float* __restrict__ v,
    float* __restrict__ partials) {
    __shared__ unsigned short As[128 * 64];
    __shared__ unsigned short Bs[128 * 64];
    const int nb = blockIdx.x;
    const int mb = blockIdx.y;
    const int m0 = mb * 128, n0 = nb * 128;
    const int t = threadIdx.x;
    const int lane = t & 63, w = t >> 6;
    const int wr = w >> 1, wc = w & 1;

    f32x4 acc[4][4];
    #pragma unroll
    for (int i = 0; i < 4; ++i)
        #pragma unroll
        for (int j = 0; j < 4; ++j) acc[i][j] = (f32x4){0.f, 0.f, 0.f, 0.f};

    for (int k0 = 0; k0 < H_; k0 += 64) {
        #pragma unroll
        for (int r = 0; r < 4; ++r) {
            const int c = r * 256 + t;
            const int row = c >> 3, slot = c & 7;
            const int sw = slot ^ (row & 7);
            uint4 da = *(const uint4*)&Ab[(size_t)(m0 + row) * H_ + k0 + slot * 8];
            *(uint4*)((char*)As + row * 128 + sw * 16) = da;
            uint4 db = *(const uint4*)&Bb[(size_t)(n0 + row) * H_ + k0 + slot * 8];
            *(uint4*)((char*)Bs + row * 128 + sw * 16) = db;
        }
        __syncthreads();
        #pragma unroll
        for (int kk = 0; kk < 2; ++kk) {
            bf16x8 a[4], b[4];
            #pragma unroll
            for (int i = 0; i < 4; ++i) {
                const int row = wr * 64 + i * 16 + (lane & 15);
                const int sw = (kk * 4 + (lane >> 4)) ^ (row & 7);
                a[i] = *(const bf16x8*)((const char*)As + row * 128 + sw * 16);
            }
            #pragma unroll
            for (int j = 0; j < 4; ++j) {
                const int row = wc * 64 + j * 16 + (lane & 15);
                const int sw = (kk * 4 + (lane >> 4)) ^ (row & 7);
                b[j] = *(const bf16x8*)((const char*)Bs + row * 128 + sw * 16);
            }
            #pragma unroll
            for (int i = 0; i < 4; ++i)
                #pragma unroll
                for (int j = 0; j < 4; ++j)
                    acc[i][j] = __builtin_amdgcn_mfma_f32_16x16x32_bf16(a[i], b[j], acc[i][j], 0, 0, 0);
        }
        __syncthreads();
    }

    float vj[4];
    #pragma unroll
    for (int j = 0; j < 4; ++j) vj[j] = v[n0 + wc * 64 + j * 16 + (lane & 15)];

    const int s = mb * 2 + wr;
    #pragma unroll
    for (int i = 0; i < 4; ++i) {
        #pragma unroll
        for (int q = 0; q < 4; ++q) {
            const int b = i * 16 + (lane >> 4) * 4 + q;
            float sum = 0.f;
            #pragma unroll
            for (int j = 0; j < 4; ++j) {
                const int n = n0 + wc * 64 + j * 16 + (lane & 15);
                sum += vj[j] * tanhf(acc[i][j][q] + hproj[b * H_ + n]);
            }
            sum += __shfl_xor(sum, 1);
            sum += __shfl_xor(sum, 2);
            sum += __shfl_xor(sum, 4);
            sum += __shfl_xor(sum, 8);
            if ((lane & 15) == 0)
                partials[((size_t)b * S_ + s) * NT_ + nb * 2 + wc] = sum;
        }
    }
}

// fp32 fallback energy (only if ws too small)
__global__ void energy_scores(const float* __restrict__ enc, const float* __restrict__ Wa,
                              const float* __restrict__ hproj, const float* __restrict__ v,
                              float* __restrict__ partials) {
    __shared__ float As[16][64];
    __shared__ float Ws[16][64];
    __shared__ float red[64][16];
    const int nt = blockIdx.x;
    const int s  = blockIdx.y;
    const int n0 = nt * 64;
    const float* Arow = enc + (size_t)s * (B_ * H_);
    const int t  = threadIdx.x;
    const int tx = t & 15, ty = t >> 4;
    float c[4][4];
    #pragma unroll
    for (int i = 0; i < 4; ++i)
        #pragma unroll
        for (int j = 0; j < 4; ++j) c[i][j] = 0.f;
    tile_acc(Arow, H_, &Wa[(size_t)n0 * (2 * H_) + H_], 2 * H_, H_, t, c, As, Ws);
    #pragma unroll
    for (int i = 0; i < 4; ++i) {
        const int b = ty * 4 + i;
        float part = 0.f;
        #pragma unroll
        for (int j = 0; j < 4; ++j) {
            const int h = n0 + tx * 4 + j;
            part += v[h] * tanhf(c[i][j] + hproj[b * H_ + h]);
        }
        red[b][tx] = part;
    }
    __syncthreads();
    if (t < 64) {
        float sum = 0.f;
        #pragma unroll
        for (int x = 0; x < 16; ++x) sum += red[t][x];
        partials[((size_t)t * S_ + s) * NT_ + nt] = sum;
    }
}

// ---------------------------------------------------------------------------
// Fused softmax + context: blockIdx.y = b, blockIdx.x = h-quarter
// ---------------------------------------------------------------------------
__global__ __launch_bounds__(256) void softmax_ctx(
    const float* __restrict__ spart, const float* __restrict__ enc,
    float* __restrict__ attn, float* __restrict__ ctx) {
    __shared__ float red[128];
    __shared__ float aw[128];
    const int b = blockIdx.y;
    const int t = threadIdx.x;
    if (t < 128) {
        float sc = 0.f;
        #pragma unroll
        for (int nt = 0; nt < NT_; ++nt) sc += spart[((size_t)b * S_ + t) * NT_ + nt];
        aw[t] = sc;
        red[t] = sc;
    }
    __syncthreads();
    for (int o = 64; o > 0; o >>= 1) {
        if (t < o) red[t] = fmaxf(red[t], red[t + o]);
        __syncthreads();
    }
    const float mx = red[0];
    __syncthreads();
    if (t < 128) { aw[t] = expf(aw[t] - mx); red[t] = aw[t]; }
    __syncthreads();
    for (int o = 64; o > 0; o >>= 1) {
        if (t < o) red[t] += red[t + o];
        __syncthreads();
    }
    const float inv = 1.f / red[0];
    if (t < 128) {
        aw[t] *= inv;
        if (blockIdx.x == 0) attn[b * S_ + t] = aw[t];
    }
    __syncthreads();
    const int h = blockIdx.x * 256 + t;
    float acc = 0.f;
    for (int s = 0; s < S_; ++s)
        acc += aw[s] * enc[((size_t)s * B_ + b) * H_ + h];
    ctx[b * H_ + h] = acc;
}

// ---------------------------------------------------------------------------
// Gate GEMMs split-K: grid (48 ntiles, 14 chunks of 256) -> P[14][64][3072]
// chunks 0-1: emb@Wx ; 2-5: z@Wz ; 6-9: ctx@Wc ; 10-13: h@Wh
// ---------------------------------------------------------------------------
__global__ void gates_splitk(const float* __restrict__ emb, const float* __restrict__ z,
                             const float* __restrict__ ctx, const float* __restrict__ h,
                             const float* __restrict__ Wx, const float* __restrict__ Wz,
                             const float* __restrict__ Wc, const float* __restrict__ Wh,
                             float* __restrict__ P) {
    __shared__ float As[16][64];
    __shared__ float Ws[16][64];
    const int n0 = blockIdx.x * 64;
    const int yc = blockIdx.y;
    const int t  = threadIdx.x;
    const int tx = t & 15, ty = t >> 4;
    const float* A; const float* W; int lda, kb;
    if (yc < 2)       { A = emb; W = Wx; lda = E_; kb = yc * 256; }
    else if (yc < 6)  { A = z;   W = Wz; lda = H_; kb = (yc - 2) * 256; }
    else if (yc < 10) { A = ctx; W = Wc; lda = H_; kb = (yc - 6) * 256; }
    else              { A = h;   W = Wh; lda = H_; kb = (yc - 10) * 256; }
    float c[4][4];
    #pragma unroll
    for (int i = 0; i < 4; ++i)
        #pragma unroll
        for (int j = 0; j < 4; ++j) c[i][j] = 0.f;
    tile_acc(&A[kb], lda, &W[(size_t)n0 * lda + kb], lda, 256, t, c, As, Ws);
    float* dst = P + (size_t)yc * B_ * H3_;
    #pragma unroll
    for (int i = 0; i < 4; ++i) {
        const int m = ty * 4 + i;
        #pragma unroll
        for (int j = 0; j < 4; ++j)
            dst[m * H3_ + n0 + tx * 4 + j] = c[i][j];
    }
}

// ---------------------------------------------------------------------------
// GRU elementwise (14-way partial reduce + biases) + fused bf16 cast of h_new
// ---------------------------------------------------------------------------
__global__ void gru_k(const float* __restrict__ P, const float* __restrict__ hlast,
                      const float* __restrict__ bx, const float* __restrict__ bz,
                      const float* __restrict__ bc, const float* __restrict__ bh,
                      float* __restrict__ hnew, unsigned short* __restrict__ hnewb) {
    const int idx = blockIdx.x * 256 + threadIdx.x;
    const int b = idx >> 10, h = idx & 1023;
    float x[3], hg[3];
    #pragma unroll
    for (int g = 0; g < 3; ++g) {
        const int col = g * H_ + h;
        float sx = bx[col] + bz[col] + bc[col];
        #pragma unroll
        for (int c = 0; c < 10; ++c) sx += P[((size_t)c * B_ + b) * H3_ + col];
        float sh = bh[col];
        #pragma unroll
        for (int c = 10; c < 14; ++c) sh += P[((size_t)c * B_ + b) * H3_ + col];
        x[g] = sx; hg[g] = sh;
    }
    const float r = 1.f / (1.f + expf(-(x[0] + hg[0])));
    const float u = 1.f / (1.f + expf(-(x[1] + hg[1])));
    const float n = tanhf(x[2] + r * hg[2]);
    const float val = (1.f - u) * n + u * hlast[idx];
    hnew[idx] = val;
    if (hnewb) hnewb[idx] = f2b(val);
}

// ---------------------------------------------------------------------------
// Wout bf16-MFMA GEMM, W fp32->bf16 converted during LDS staging
// ---------------------------------------------------------------------------
__global__ __launch_bounds__(256) void wout_mfma(
    const unsigned short* __restrict__ Ab, const float* __restrict__ W,
    const float* __restrict__ bias, float* __restrict__ C) {
    __shared__ unsigned short As[64 * 64];
    __shared__ unsigned short Bs[64 * 64];
    const int n0 = blockIdx.x * 64;
    const int t = threadIdx.x;
    const int lane = t & 63, w = t >> 6;
    const int wr = w >> 1, wc = w & 1;

    f32x4 acc[2][2];
    #pragma unroll
    for (int i = 0; i < 2; ++i)
        #pragma unroll
        for (int j = 0; j < 2; ++j) acc[i][j] = (f32x4){0.f, 0.f, 0.f, 0.f};

    for (int k0 = 0; k0 < H_; k0 += 64) {
        #pragma unroll
        for (int r = 0; r < 2; ++r) {
            const int c = r * 256 + t;
            const int row = c >> 3, slot = c & 7;
            const int sw = slot ^ (row & 7);
            uint4 da = *(const uint4*)&Ab[(size_t)row * H_ + k0 + slot * 8];
            *(uint4*)((char*)As + row * 128 + sw * 16) = da;
        }
        #pragma unroll
        for (int r = 0; r < 4; ++r) {
            const int c = r * 256 + t;
            const int row = c >> 4, q4 = c & 15;
            const float4 wv = *(const float4*)&W[(size_t)(n0 + row) * H_ + k0 + q4 * 4];
            uint2 pk;
            pk.x = (unsigned int)f2b(wv.x) | ((unsigned int)f2b(wv.y) << 16);
            pk.y = (unsigned int)f2b(wv.z) | ((unsigned int)f2b(wv.w) << 16);
            const int slot = q4 >> 1, half = q4 & 1;
            const int sw = slot ^ (row & 7);
            *(uint2*)((char*)Bs + row * 128 + sw * 16 + half * 8) = pk;
        }
        __syncthreads();
        #pragma unroll
        for (int kk = 0; kk < 2; ++kk) {
            bf16x8 a[2], b[2];
            #pragma unroll
            for (int i = 0; i < 2; ++i) {
                const int row = wr * 32 + i * 16 + (lane & 15);
                const int sw = (kk * 4 + (lane >> 4)) ^ (row & 7);
                a[i] = *(const bf16x8*)((const char*)As + row * 128 + sw * 16);
            }
            #pragma unroll
            for (int j = 0; j < 2; ++j) {
                const int row = wc * 32 + j * 16 + (lane & 15);
                const int sw = (kk * 4 + (lane >> 4)) ^ (row & 7);
                b[j] = *(const bf16x8*)((const char*)Bs + row * 128 + sw * 16);
            }
            #pragma unroll
            for (int i = 0; i < 2; ++i)
                #pragma unroll
                for (int j = 0; j < 2; ++j)
                    acc[i][j] = __builtin_amdgcn_mfma_f32_16x16x32_bf16(a[i], b[j], acc[i][j], 0, 0, 0);
        }
        __syncthreads();
    }

    #pragma unroll
    for (int i = 0; i < 2; ++i)
        #pragma unroll
        for (int j = 0; j < 2; ++j) {
            const int n = n0 + wc * 32 + j * 16 + (lane & 15);
            const float bn = bias[n];
            #pragma unroll
            for (int q = 0; q < 4; ++q) {
                const int m = wr * 32 + i * 16 + (lane >> 4) * 4 + q;
                C[(size_t)m * V_ + n] = acc[i][j][q] + bn;
            }
        }
}

// fp32 fallback Wout GEMM
__global__ void gemm_nt(const float* __restrict__ A, const float* __restrict__ W,
                        const float* __restrict__ bias, float* __restrict__ C,
                        int N, int K) {
    __shared__ float As[16][64];
    __shared__ float Ws[16][64];
    const int n0 = blockIdx.x * 64;
    const int t  = threadIdx.x;
    const int tx = t & 15, ty = t >> 4;
    float c[4][4];
    #pragma unroll
    for (int i = 0; i < 4; ++i)
        #pragma unroll
        for (int j = 0; j < 4; ++j) c[i][j] = 0.f;
    tile_acc(A, K, &W[(size_t)n0 * K], K, K, t, c, As, Ws);
    #pragma unroll
    for (int i = 0; i < 4; ++i) {
        const int m = ty * 4 + i;
        #pragma unroll
        for (int j = 0; j < 4; ++j) {
            const int n = n0 + tx * 4 + j;
            C[m * N + n] = c[i][j] + bias[n];
        }
    }
}

extern "C" void kernel_launch(void* const* d_in, const int* in_sizes, int n_in,
                              void* d_out, int out_size, void* d_ws, size_t ws_size,
                              hipStream_t stream) {
    const float* emb   = (const float*)d_in[0];
    const float* hid   = (const float*)d_in[1];
    const float* enc   = (const float*)d_in[2];
    const float* z     = (const float*)d_in[3];
    const float* Wa    = (const float*)d_in[4];
    const float* ba    = (const float*)d_in[5];
    const float* v     = (const float*)d_in[6];
    const float* Wx    = (const float*)d_in[7];
    const float* bx    = (const float*)d_in[8];
    const float* Wh    = (const float*)d_in[9];
    const float* bh    = (const float*)d_in[10];
    const float* Wc    = (const float*)d_in[11];
    const float* bc    = (const float*)d_in[12];
    const float* Wz    = (const float*)d_in[13];
    const float* bz    = (const float*)d_in[14];
    const float* Wout  = (const float*)d_in[15];
    const float* bout  = (const float*)d_in[16];

    float* out  = (float*)d_out;
    float* hnew = out + (size_t)B_ * V_;
    float* attn = hnew + (size_t)B_ * H_;

    // ws layout — fully disjoint
    float* hproj = (float*)d_ws;                          // 64K f
    float* spart = hproj + (size_t)B_ * H_;               // 128K f
    float* ctx   = spart + (size_t)B_ * S_ * NT_;         // 64K f
    float* hpp   = ctx + (size_t)B_ * H_;                 // 512K f
    float* P     = hpp + (size_t)8 * B_ * H_;             // NGC*192K f
    float* fend  = P + (size_t)NGC * B_ * H3_;
    unsigned short* hnewb = (unsigned short*)fend;        // 64K s
    unsigned short* encb  = hnewb + (size_t)B_ * H_;      // 8.39M s
    unsigned short* wa2b  = encb + (size_t)S_ * B_ * H_;  // 1.05M s
    const size_t need = (size_t)((char*)(wa2b + (size_t)H_ * H_) - (char*)d_ws);

    const float* hlast = hid;
    dim3 blk(256);

    const bool fast = (ws_size >= need);
    if (fast) {
        prologue<<<dim3(4736), blk, 0, stream>>>(enc, Wa, hlast, encb, wa2b, hpp);
        reduce_hproj<<<dim3((B_ * H_) / 256), blk, 0, stream>>>(hpp, ba, hproj);
        energy_mfma<<<dim3(H_ / 128, (S_ * B_) / 128), blk, 0, stream>>>(encb, wa2b, hproj, v, spart);
        softmax_ctx<<<dim3(H_ / 256, B_), blk, 0, stream>>>(spart, enc, attn, ctx);
        gates_splitk<<<dim3(H3_ / 64, NGC), blk, 0, stream>>>(emb, z, ctx, hlast,
                                                              Wx, Wz, Wc, Wh, P);
        gru_k<<<dim3((B_ * H_) / 256), blk, 0, stream>>>(P, hlast, bx, bz, bc, bh, hnew, hnewb);
        wout_mfma<<<dim3(V_ / 64), blk, 0, stream>>>(hnewb, Wout, bout, out);
    } else {
        hproj_splitk<<<dim3(H_ / 64, 8), blk, 0, stream>>>(hlast, Wa, hpp);
        reduce_hproj<<<dim3((B_ * H_) / 256), blk, 0, stream>>>(hpp, ba, hproj);
        energy_scores<<<dim3(NT_, S_), blk, 0, stream>>>(enc, Wa, hproj, v, spart);
        softmax_ctx<<<dim3(H_ / 256, B_), blk, 0, stream>>>(spart, enc, attn, ctx);
        gates_splitk<<<dim3(H3_ / 64, NGC), blk, 0, stream>>>(emb, z, ctx, hlast,
                                                              Wx, Wz, Wc, Wh, P);
        gru_k<<<dim3((B_ * H_) / 256), blk, 0, stream>>>(P, hlast, bx, bz, bc, bh, hnew, nullptr);
        gemm_nt<<<dim3(V_ / 64), blk, 0, stream>>>(hnew, Wout, bout, out, V_, H_);
    }
}

// Round 8
// 118.717 us; speedup vs baseline: 1.5060x; 1.0921x over previous
//
#include <hip/hip_runtime.h>
#include <hip/hip_bf16.h>
#include <math.h>

#define B_  64
#define S_  128
#define E_  512
#define H_  1024
#define V_  32000
#define H3_ 3072
#define NT_ 16
#define NGC 14   // gate split-K chunks of 256

typedef __attribute__((ext_vector_type(8))) short bf16x8;
typedef __attribute__((ext_vector_type(4))) float f32x4;

__device__ __forceinline__ unsigned short f2b(float f) {
    unsigned int u = __builtin_bit_cast(unsigned int, f);
    u = (u + 0x7fffu + ((u >> 16) & 1u)) >> 16;
    return (unsigned short)u;
}

// ---------------------------------------------------------------------------
// fp32 64x64-tile inner product over a K span, register-prefetch double buffer
// ---------------------------------------------------------------------------
__device__ __forceinline__ void tile_acc(const float* __restrict__ A, int lda,
                                         const float* __restrict__ Wrow0, int ldw,
                                         int kspan, int t, float c[4][4],
                                         float (*As)[64], float (*Ws)[64]) {
    const int tx = t & 15, ty = t >> 4;
    const int lm = t >> 2;
    const int lk = (t & 3) * 4;
    float4 av = *(const float4*)&A[lm * lda + lk];
    float4 wv = *(const float4*)&Wrow0[(size_t)lm * ldw + lk];
    for (int k0 = 0; k0 < kspan; k0 += 16) {
        As[lk + 0][lm] = av.x; As[lk + 1][lm] = av.y;
        As[lk + 2][lm] = av.z; As[lk + 3][lm] = av.w;
        Ws[lk + 0][lm] = wv.x; Ws[lk + 1][lm] = wv.y;
        Ws[lk + 2][lm] = wv.z; Ws[lk + 3][lm] = wv.w;
        __syncthreads();
        if (k0 + 16 < kspan) {
            av = *(const float4*)&A[lm * lda + k0 + 16 + lk];
            wv = *(const float4*)&Wrow0[(size_t)lm * ldw + k0 + 16 + lk];
        }
        #pragma unroll
        for (int k = 0; k < 16; ++k) {
            float4 a = *(const float4*)&As[k][ty * 4];
            float4 w = *(const float4*)&Ws[k][tx * 4];
            c[0][0] += a.x * w.x; c[0][1] += a.x * w.y; c[0][2] += a.x * w.z; c[0][3] += a.x * w.w;
            c[1][0] += a.y * w.x; c[1][1] += a.y * w.y; c[1][2] += a.y * w.z; c[1][3] += a.y * w.w;
            c[2][0] += a.z * w.x; c[2][1] += a.z * w.y; c[2][2] += a.z * w.z; c[2][3] += a.z * w.w;
            c[3][0] += a.w * w.x; c[3][1] += a.w * w.y; c[3][2] += a.w * w.z; c[3][3] += a.w * w.w;
        }
        __syncthreads();
    }
}

__device__ __forceinline__ void hproj_body(int bx, int by, const float* __restrict__ h,
                                           const float* __restrict__ Wa, float* __restrict__ hpp,
                                           int t, float (*As)[64], float (*Ws)[64]) {
    const int n0 = bx * 64;
    const int kb = by * 128;
    const int tx = t & 15, ty = t >> 4;
    float c[4][4];
    #pragma unroll
    for (int i = 0; i < 4; ++i)
        #pragma unroll
        for (int j = 0; j < 4; ++j) c[i][j] = 0.f;
    tile_acc(&h[kb], H_, &Wa[(size_t)n0 * (2 * H_) + kb], 2 * H_, 128, t, c, As, Ws);
    float* dst = hpp + (size_t)by * B_ * H_;
    #pragma unroll
    for (int i = 0; i < 4; ++i) {
        const int m = ty * 4 + i;
        #pragma unroll
        for (int j = 0; j < 4; ++j)
            dst[m * H_ + n0 + tx * 4 + j] = c[i][j];
    }
}

// ---------------------------------------------------------------------------
// Slim prologue: [0,512) cast Wa2 -> bf16 ; [512,640) hproj split-K partials.
// (enc cast is now fused into energy_mfma's LDS staging.)
// ---------------------------------------------------------------------------
__global__ __launch_bounds__(256) void prologue(
    const float* __restrict__ Wa, const float* __restrict__ h,
    unsigned short* __restrict__ wa2b, float* __restrict__ hpp) {
    __shared__ float As[16][64];
    __shared__ float Ws[16][64];
    const int bid = blockIdx.x;
    const int t = threadIdx.x;
    if (bid < 512) {
        const int id = bid * 256 + t;
        const int n = id >> 7;
        const int kk = (id & 127) * 8;
        const float* src = &Wa[(size_t)n * (2 * H_) + H_ + kk];
        float4 a = *(const float4*)src;
        float4 b = *(const float4*)(src + 4);
        unsigned short o[8] = { f2b(a.x), f2b(a.y), f2b(a.z), f2b(a.w),
                                f2b(b.x), f2b(b.y), f2b(b.z), f2b(b.w) };
        *(uint4*)&wa2b[(size_t)n * H_ + kk] = *(uint4*)o;
    } else {
        const int id = bid - 512;
        hproj_body(id & 15, id >> 4, h, Wa, hpp, t, As, Ws);
    }
}

// standalone hproj (fallback path)
__global__ void hproj_splitk(const float* __restrict__ h, const float* __restrict__ Wa,
                             float* __restrict__ hpp) {
    __shared__ float As[16][64];
    __shared__ float Ws[16][64];
    hproj_body(blockIdx.x, blockIdx.y, h, Wa, hpp, threadIdx.x, As, Ws);
}

__global__ void reduce_hproj(const float* __restrict__ hpp, const float* __restrict__ ba,
                             float* __restrict__ hproj) {
    const int idx = blockIdx.x * 256 + threadIdx.x;
    const int hh = idx & 1023;
    float s = ba[hh];
    #pragma unroll
    for (int c = 0; c < 8; ++c) s += hpp[(size_t)c * B_ * H_ + idx];
    hproj[idx] = s;
}

// ---------------------------------------------------------------------------
// bf16 MFMA energy+scores: 128x128 tile, BK=64, 4 waves, 16x16x32 MFMA.
// A (enc) is fp32, cast to bf16 during LDS staging. Grid (x=mb, y=nb) so all
// nb-blocks sharing an A-tile land on one XCD (bid%8 == mb%8) -> L2 reuse.
// ---------------------------------------------------------------------------
__global__ __launch_bounds__(256) void energy_mfma(
    const float* __restrict__ enc, const unsigned short* __restrict__ Bb,
    const float* __restrict__ hproj, const float* __restrict__ v,
    float* __restrict__ partials) {
    __shared__ unsigned short As[128 * 64];   // 16 KB
    __shared__ unsigned short Bs[128 * 64];
    const int mb = blockIdx.x;                // 0..63
    const int nb = blockIdx.y;                // 0..7
    const int m0 = mb * 128, n0 = nb * 128;
    const int t = threadIdx.x;
    const int lane = t & 63, w = t >> 6;
    const int wr = w >> 1, wc = w & 1;

    f32x4 acc[4][4];
    #pragma unroll
    for (int i = 0; i < 4; ++i)
        #pragma unroll
        for (int j = 0; j < 4; ++j) acc[i][j] = (f32x4){0.f, 0.f, 0.f, 0.f};

    for (int k0 = 0; k0 < H_; k0 += 64) {
        // stage A: fp32 -> bf16; 128 rows x 16 float4 = 2048 chunks, 8/thread
        #pragma unroll
        for (int r = 0; r < 8; ++r) {
            const int c = r * 256 + t;
            const int row = c >> 4, q4 = c & 15;
            const float4 av = *(const float4*)&enc[(size_t)(m0 + row) * H_ + k0 + q4 * 4];
            uint2 pk;
            pk.x = (unsigned int)f2b(av.x) | ((unsigned int)f2b(av.y) << 16);
            pk.y = (unsigned int)f2b(av.z) | ((unsigned int)f2b(av.w) << 16);
            const int slot = q4 >> 1, half = q4 & 1;
            const int sw = slot ^ (row & 7);
            *(uint2*)((char*)As + row * 128 + sw * 16 + half * 8) = pk;
        }
        // stage B: already bf16; 128 rows x 8 slots = 1024 chunks, 4/thread
        #pragma unroll
        for (int r = 0; r < 4; ++r) {
            const int c = r * 256 + t;
            const int row = c >> 3, slot = c & 7;
            const int sw = slot ^ (row & 7);
            uint4 db = *(const uint4*)&Bb[(size_t)(n0 + row) * H_ + k0 + slot * 8];
            *(uint4*)((char*)Bs + row * 128 + sw * 16) = db;
        }
        __syncthreads();
        #pragma unroll
        for (int kk = 0; kk < 2; ++kk) {
            bf16x8 a[4], b[4];
            #pragma unroll
            for (int i = 0; i < 4; ++i) {
                const int row = wr * 64 + i * 16 + (lane & 15);
                const int sw = (kk * 4 + (lane >> 4)) ^ (row & 7);
                a[i] = *(const bf16x8*)((const char*)As + row * 128 + sw * 16);
            }
            #pragma unroll
            for (int j = 0; j < 4; ++j) {
                const int row = wc * 64 + j * 16 + (lane & 15);
                const int sw = (kk * 4 + (lane >> 4)) ^ (row & 7);
                b[j] = *(const bf16x8*)((const char*)Bs + row * 128 + sw * 16);
            }
            #pragma unroll
            for (int i = 0; i < 4; ++i)
                #pragma unroll
                for (int j = 0; j < 4; ++j)
                    acc[i][j] = __builtin_amdgcn_mfma_f32_16x16x32_bf16(a[i], b[j], acc[i][j], 0, 0, 0);
        }
        __syncthreads();
    }

    float vj[4];
    #pragma unroll
    for (int j = 0; j < 4; ++j) vj[j] = v[n0 + wc * 64 + j * 16 + (lane & 15)];

    const int s = mb * 2 + wr;
    #pragma unroll
    for (int i = 0; i < 4; ++i) {
        #pragma unroll
        for (int q = 0; q < 4; ++q) {
            const int b = i * 16 + (lane >> 4) * 4 + q;
            float sum = 0.f;
            #pragma unroll
            for (int j = 0; j < 4; ++j) {
                const int n = n0 + wc * 64 + j * 16 + (lane & 15);
                sum += vj[j] * tanhf(acc[i][j][q] + hproj[b * H_ + n]);
            }
            sum += __shfl_xor(sum, 1);
            sum += __shfl_xor(sum, 2);
            sum += __shfl_xor(sum, 4);
            sum += __shfl_xor(sum, 8);
            if ((lane & 15) == 0)
                partials[((size_t)b * S_ + s) * NT_ + nb * 2 + wc] = sum;
        }
    }
}

// fp32 fallback energy (only if ws too small)
__global__ void energy_scores(const float* __restrict__ enc, const float* __restrict__ Wa,
                              const float* __restrict__ hproj, const float* __restrict__ v,
                              float* __restrict__ partials) {
    __shared__ float As[16][64];
    __shared__ float Ws[16][64];
    __shared__ float red[64][16];
    const int nt = blockIdx.x;
    const int s  = blockIdx.y;
    const int n0 = nt * 64;
    const float* Arow = enc + (size_t)s * (B_ * H_);
    const int t  = threadIdx.x;
    const int tx = t & 15, ty = t >> 4;
    float c[4][4];
    #pragma unroll
    for (int i = 0; i < 4; ++i)
        #pragma unroll
        for (int j = 0; j < 4; ++j) c[i][j] = 0.f;
    tile_acc(Arow, H_, &Wa[(size_t)n0 * (2 * H_) + H_], 2 * H_, H_, t, c, As, Ws);
    #pragma unroll
    for (int i = 0; i < 4; ++i) {
        const int b = ty * 4 + i;
        float part = 0.f;
        #pragma unroll
        for (int j = 0; j < 4; ++j) {
            const int h = n0 + tx * 4 + j;
            part += v[h] * tanhf(c[i][j] + hproj[b * H_ + h]);
        }
        red[b][tx] = part;
    }
    __syncthreads();
    if (t < 64) {
        float sum = 0.f;
        #pragma unroll
        for (int x = 0; x < 16; ++x) sum += red[t][x];
        partials[((size_t)t * S_ + s) * NT_ + nt] = sum;
    }
}

// ---------------------------------------------------------------------------
// Fused softmax + context: blockIdx.y = b, blockIdx.x = h-quarter
// ---------------------------------------------------------------------------
__global__ __launch_bounds__(256) void softmax_ctx(
    const float* __restrict__ spart, const float* __restrict__ enc,
    float* __restrict__ attn, float* __restrict__ ctx) {
    __shared__ float red[128];
    __shared__ float aw[128];
    const int b = blockIdx.y;
    const int t = threadIdx.x;
    if (t < 128) {
        float sc = 0.f;
        #pragma unroll
        for (int nt = 0; nt < NT_; ++nt) sc += spart[((size_t)b * S_ + t) * NT_ + nt];
        aw[t] = sc;
        red[t] = sc;
    }
    __syncthreads();
    for (int o = 64; o > 0; o >>= 1) {
        if (t < o) red[t] = fmaxf(red[t], red[t + o]);
        __syncthreads();
    }
    const float mx = red[0];
    __syncthreads();
    if (t < 128) { aw[t] = expf(aw[t] - mx); red[t] = aw[t]; }
    __syncthreads();
    for (int o = 64; o > 0; o >>= 1) {
        if (t < o) red[t] += red[t + o];
        __syncthreads();
    }
    const float inv = 1.f / red[0];
    if (t < 128) {
        aw[t] *= inv;
        if (blockIdx.x == 0) attn[b * S_ + t] = aw[t];
    }
    __syncthreads();
    const int h = blockIdx.x * 256 + t;
    float acc = 0.f;
    for (int s = 0; s < S_; ++s)
        acc += aw[s] * enc[((size_t)s * B_ + b) * H_ + h];
    ctx[b * H_ + h] = acc;
}

// ---------------------------------------------------------------------------
// Gate GEMMs split-K: grid (48 ntiles, 14 chunks of 256) -> P[14][64][3072]
// chunks 0-1: emb@Wx ; 2-5: z@Wz ; 6-9: ctx@Wc ; 10-13: h@Wh
// ---------------------------------------------------------------------------
__global__ void gates_splitk(const float* __restrict__ emb, const float* __restrict__ z,
                             const float* __restrict__ ctx, const float* __restrict__ h,
                             const float* __restrict__ Wx, const float* __restrict__ Wz,
                             const float* __restrict__ Wc, const float* __restrict__ Wh,
                             float* __restrict__ P) {
    __shared__ float As[16][64];
    __shared__ float Ws[16][64];
    const int n0 = blockIdx.x * 64;
    const int yc = blockIdx.y;
    const int t  = threadIdx.x;
    const int tx = t & 15, ty = t >> 4;
    const float* A; const float* W; int lda, kb;
    if (yc < 2)       { A = emb; W = Wx; lda = E_; kb = yc * 256; }
    else if (yc < 6)  { A = z;   W = Wz; lda = H_; kb = (yc - 2) * 256; }
    else if (yc < 10) { A = ctx; W = Wc; lda = H_; kb = (yc - 6) * 256; }
    else              { A = h;   W = Wh; lda = H_; kb = (yc - 10) * 256; }
    float c[4][4];
    #pragma unroll
    for (int i = 0; i < 4; ++i)
        #pragma unroll
        for (int j = 0; j < 4; ++j) c[i][j] = 0.f;
    tile_acc(&A[kb], lda, &W[(size_t)n0 * lda + kb], lda, 256, t, c, As, Ws);
    float* dst = P + (size_t)yc * B_ * H3_;
    #pragma unroll
    for (int i = 0; i < 4; ++i) {
        const int m = ty * 4 + i;
        #pragma unroll
        for (int j = 0; j < 4; ++j)
            dst[m * H3_ + n0 + tx * 4 + j] = c[i][j];
    }
}

// ---------------------------------------------------------------------------
// GRU elementwise (14-way partial reduce + biases) + fused bf16 cast of h_new
// ---------------------------------------------------------------------------
__global__ void gru_k(const float* __restrict__ P, const float* __restrict__ hlast,
                      const float* __restrict__ bx, const float* __restrict__ bz,
                      const float* __restrict__ bc, const float* __restrict__ bh,
                      float* __restrict__ hnew, unsigned short* __restrict__ hnewb) {
    const int idx = blockIdx.x * 256 + threadIdx.x;
    const int b = idx >> 10, h = idx & 1023;
    float x[3], hg[3];
    #pragma unroll
    for (int g = 0; g < 3; ++g) {
        const int col = g * H_ + h;
        float sx = bx[col] + bz[col] + bc[col];
        #pragma unroll
        for (int c = 0; c < 10; ++c) sx += P[((size_t)c * B_ + b) * H3_ + col];
        float sh = bh[col];
        #pragma unroll
        for (int c = 10; c < 14; ++c) sh += P[((size_t)c * B_ + b) * H3_ + col];
        x[g] = sx; hg[g] = sh;
    }
    const float r = 1.f / (1.f + expf(-(x[0] + hg[0])));
    const float u = 1.f / (1.f + expf(-(x[1] + hg[1])));
    const float n = tanhf(x[2] + r * hg[2]);
    const float val = (1.f - u) * n + u * hlast[idx];
    hnew[idx] = val;
    if (hnewb) hnewb[idx] = f2b(val);
}

// ---------------------------------------------------------------------------
// Wout bf16-MFMA GEMM, W fp32->bf16 converted during LDS staging
// ---------------------------------------------------------------------------
__global__ __launch_bounds__(256) void wout_mfma(
    const unsigned short* __restrict__ Ab, const float* __restrict__ W,
    const float* __restrict__ bias, float* __restrict__ C) {
    __shared__ unsigned short As[64 * 64];
    __shared__ unsigned short Bs[64 * 64];
    const int n0 = blockIdx.x * 64;
    const int t = threadIdx.x;
    const int lane = t & 63, w = t >> 6;
    const int wr = w >> 1, wc = w & 1;

    f32x4 acc[2][2];
    #pragma unroll
    for (int i = 0; i < 2; ++i)
        #pragma unroll
        for (int j = 0; j < 2; ++j) acc[i][j] = (f32x4){0.f, 0.f, 0.f, 0.f};

    for (int k0 = 0; k0 < H_; k0 += 64) {
        #pragma unroll
        for (int r = 0; r < 2; ++r) {
            const int c = r * 256 + t;
            const int row = c >> 3, slot = c & 7;
            const int sw = slot ^ (row & 7);
            uint4 da = *(const uint4*)&Ab[(size_t)row * H_ + k0 + slot * 8];
            *(uint4*)((char*)As + row * 128 + sw * 16) = da;
        }
        #pragma unroll
        for (int r = 0; r < 4; ++r) {
            const int c = r * 256 + t;
            const int row = c >> 4, q4 = c & 15;
            const float4 wv = *(const float4*)&W[(size_t)(n0 + row) * H_ + k0 + q4 * 4];
            uint2 pk;
            pk.x = (unsigned int)f2b(wv.x) | ((unsigned int)f2b(wv.y) << 16);
            pk.y = (unsigned int)f2b(wv.z) | ((unsigned int)f2b(wv.w) << 16);
            const int slot = q4 >> 1, half = q4 & 1;
            const int sw = slot ^ (row & 7);
            *(uint2*)((char*)Bs + row * 128 + sw * 16 + half * 8) = pk;
        }
        __syncthreads();
        #pragma unroll
        for (int kk = 0; kk < 2; ++kk) {
            bf16x8 a[2], b[2];
            #pragma unroll
            for (int i = 0; i < 2; ++i) {
                const int row = wr * 32 + i * 16 + (lane & 15);
                const int sw = (kk * 4 + (lane >> 4)) ^ (row & 7);
                a[i] = *(const bf16x8*)((const char*)As + row * 128 + sw * 16);
            }
            #pragma unroll
            for (int j = 0; j < 2; ++j) {
                const int row = wc * 32 + j * 16 + (lane & 15);
                const int sw = (kk * 4 + (lane >> 4)) ^ (row & 7);
                b[j] = *(const bf16x8*)((const char*)Bs + row * 128 + sw * 16);
            }
            #pragma unroll
            for (int i = 0; i < 2; ++i)
                #pragma unroll
                for (int j = 0; j < 2; ++j)
                    acc[i][j] = __builtin_amdgcn_mfma_f32_16x16x32_bf16(a[i], b[j], acc[i][j], 0, 0, 0);
        }
        __syncthreads();
    }

    #pragma unroll
    for (int i = 0; i < 2; ++i)
        #pragma unroll
        for (int j = 0; j < 2; ++j) {
            const int n = n0 + wc * 32 + j * 16 + (lane & 15);
            const float bn = bias[n];
            #pragma unroll
            for (int q = 0; q < 4; ++q) {
                const int m = wr * 32 + i * 16 + (lane >> 4) * 4 + q;
                C[(size_t)m * V_ + n] = acc[i][j][q] + bn;
            }
        }
}

// fp32 fallback Wout GEMM
__global__ void gemm_nt(const float* __restrict__ A, const float* __restrict__ W,
                        const float* __restrict__ bias, float* __restrict__ C,
                        int N, int K) {
    __shared__ float As[16][64];
    __shared__ float Ws[16][64];
    const int n0 = blockIdx.x * 64;
    const int t  = threadIdx.x;
    const int tx = t & 15, ty = t >> 4;
    float c[4][4];
    #pragma unroll
    for (int i = 0; i < 4; ++i)
        #pragma unroll
        for (int j = 0; j < 4; ++j) c[i][j] = 0.f;
    tile_acc(A, K, &W[(size_t)n0 * K], K, K, t, c, As, Ws);
    #pragma unroll
    for (int i = 0; i < 4; ++i) {
        const int m = ty * 4 + i;
        #pragma unroll
        for (int j = 0; j < 4; ++j) {
            const int n = n0 + tx * 4 + j;
            C[m * N + n] = c[i][j] + bias[n];
        }
    }
}

extern "C" void kernel_launch(void* const* d_in, const int* in_sizes, int n_in,
                              void* d_out, int out_size, void* d_ws, size_t ws_size,
                              hipStream_t stream) {
    const float* emb   = (const float*)d_in[0];
    const float* hid   = (const float*)d_in[1];
    const float* enc   = (const float*)d_in[2];
    const float* z     = (const float*)d_in[3];
    const float* Wa    = (const float*)d_in[4];
    const float* ba    = (const float*)d_in[5];
    const float* v     = (const float*)d_in[6];
    const float* Wx    = (const float*)d_in[7];
    const float* bx    = (const float*)d_in[8];
    const float* Wh    = (const float*)d_in[9];
    const float* bh    = (const float*)d_in[10];
    const float* Wc    = (const float*)d_in[11];
    const float* bc    = (const float*)d_in[12];
    const float* Wz    = (const float*)d_in[13];
    const float* bz    = (const float*)d_in[14];
    const float* Wout  = (const float*)d_in[15];
    const float* bout  = (const float*)d_in[16];

    float* out  = (float*)d_out;
    float* hnew = out + (size_t)B_ * V_;
    float* attn = hnew + (size_t)B_ * H_;

    // ws layout — fully disjoint (no encb anymore)
    float* hproj = (float*)d_ws;                          // 64K f
    float* spart = hproj + (size_t)B_ * H_;               // 128K f
    float* ctx   = spart + (size_t)B_ * S_ * NT_;         // 64K f
    float* hpp   = ctx + (size_t)B_ * H_;                 // 512K f
    float* P     = hpp + (size_t)8 * B_ * H_;             // NGC*192K f
    float* fend  = P + (size_t)NGC * B_ * H3_;
    unsigned short* hnewb = (unsigned short*)fend;        // 64K s
    unsigned short* wa2b  = hnewb + (size_t)B_ * H_;      // 1.05M s
    const size_t need = (size_t)((char*)(wa2b + (size_t)H_ * H_) - (char*)d_ws);

    const float* hlast = hid;
    dim3 blk(256);

    const bool fast = (ws_size >= need);
    if (fast) {
        prologue<<<dim3(640), blk, 0, stream>>>(Wa, hlast, wa2b, hpp);
        reduce_hproj<<<dim3((B_ * H_) / 256), blk, 0, stream>>>(hpp, ba, hproj);
        energy_mfma<<<dim3((S_ * B_) / 128, H_ / 128), blk, 0, stream>>>(enc, wa2b, hproj, v, spart);
        softmax_ctx<<<dim3(H_ / 256, B_), blk, 0, stream>>>(spart, enc, attn, ctx);
        gates_splitk<<<dim3(H3_ / 64, NGC), blk, 0, stream>>>(emb, z, ctx, hlast,
                                                              Wx, Wz, Wc, Wh, P);
        gru_k<<<dim3((B_ * H_) / 256), blk, 0, stream>>>(P, hlast, bx, bz, bc, bh, hnew, hnewb);
        wout_mfma<<<dim3(V_ / 64), blk, 0, stream>>>(hnewb, Wout, bout, out);
    } else {
        hproj_splitk<<<dim3(H_ / 64, 8), blk, 0, stream>>>(hlast, Wa, hpp);
        reduce_hproj<<<dim3((B_ * H_) / 256), blk, 0, stream>>>(hpp, ba, hproj);
        energy_scores<<<dim3(NT_, S_), blk, 0, stream>>>(enc, Wa, hproj, v, spart);
        softmax_ctx<<<dim3(H_ / 256, B_), blk, 0, stream>>>(spart, enc, attn, ctx);
        gates_splitk<<<dim3(H3_ / 64, NGC), blk, 0, stream>>>(emb, z, ctx, hlast,
                                                              Wx, Wz, Wc, Wh, P);
        gru_k<<<dim3((B_ * H_) / 256), blk, 0, stream>>>(P, hlast, bx, bz, bc, bh, hnew, nullptr);
        gemm_nt<<<dim3(V_ / 64), blk, 0, stream>>>(hnew, Wout, bout, out, V_, H_);
    }
}